// Round 12
// baseline (199.718 us; speedup 1.0000x reference)
//
#include <hip/hip_runtime.h>

typedef __bf16 bf16x8 __attribute__((ext_vector_type(8)));
typedef float f32x4 __attribute__((ext_vector_type(4)));

namespace {
constexpr int kCX = 352, kCY = 400;
constexpr int kCL = 2 * kCY * kCX;   // 281600 voxels (CZ==1), < 2^19
constexpr float kVX = 0.2f, kVY = 0.2f;
constexpr float kXOFF = 0.1f;    // VX/2 + X0
constexpr float kYOFF = -39.9f;  // VY/2 + Y0
constexpr float kZOFF = -1.0f;   // VZ/2 + Z0 (cz==0 always)
constexpr int P = 64;            // sorted points per fused block
constexpr int W = 89;            // window entries: 1 + P + 24 extension
constexpr int FrW = 90;          // Fraw width (reads bounded by ecap <= 88)
constexpr int NPmax = 76;        // capacity incl. voxel-straddle (max run ~12)
constexpr int NBLK = kCL / 256;  // 1100 alloc blocks (1 thread : 1 voxel)
constexpr int NPREP = 5;         // extra alloczero blocks: weight-frag prep
constexpr int PhS = 68;          // Ph/Vh row stride u16 (136B = 34dw, 2-way free)
}

__device__ __forceinline__ unsigned int cvt_pk_bf16(float lo, float hi) {
  unsigned int r;
  asm("v_cvt_pk_bf16_f32 %0, %1, %2" : "=v"(r) : "v"(lo), "v"(hi));
  return r;  // packed {hi16=bf16(hi), lo16=bf16(lo)}, RNE
}

union BF8 { unsigned short u[8]; bf16x8 v; };

__device__ __forceinline__ int voxel_of(int4 c) {
  return ((c.x + c.y) * kCY + c.z) * kCX + c.w;  // CZ==1
}

// ---------------- hist: counts + {vid | rank<<19} cache ----------------
__global__ void k_hist(const int4* __restrict__ coors,
                       unsigned int* __restrict__ cnt,
                       unsigned int* __restrict__ vid, int n) {
  int p = blockIdx.x * blockDim.x + threadIdx.x;
  if (p >= n) return;
  int v = voxel_of(coors[p]);
  unsigned int r = atomicAdd(&cnt[v], 1u);
  vid[p] = (unsigned int)v | (r << 19);
}

// ------- alloc: block-local scan + ONE relaxed atomicAdd per block --------
// Blocks >= NBLK prepack W1/W2 into per-lane bf16 hi/lo MFMA fragments.
// wB layout (uint4 units): [B1hh 4*64 | B1l0 4*64 | B2h 16*64 | B2l 16*64]
__global__ __launch_bounds__(256) void k_alloczero(
    const unsigned int* __restrict__ cnt,
    unsigned int* __restrict__ total,
    unsigned int* __restrict__ cursor,
    float4* __restrict__ out4,
    const float* __restrict__ W1,
    const float* __restrict__ W2,
    uint4* __restrict__ wB) {
  int b = blockIdx.x;
  if (b >= NBLK) {  // ---- weight prep path ----
    int idx = (b - NBLK) * 256 + threadIdx.x;
    if (idx < 1024) {  // B2 frags: idx = (cb*4+kb)*64 + l
      int kb = (idx >> 6) & 3, l = idx & 63;
      int colw = (idx >> 8) * 16 + (l & 15), qw = l >> 4;
      BF8 h, lo;
#pragma unroll
      for (int i = 0; i < 8; ++i) {
        float w = W2[(kb * 32 + qw * 8 + i) * 64 + colw];
        unsigned int u = __float_as_uint(w);
        h.u[i] = (unsigned short)(u >> 16);           // trunc hi
        float e = w - __uint_as_float(u & 0xffff0000u);
        lo.u[i] = (unsigned short)(__float_as_uint(e) >> 16);  // resid lo
      }
      wB[512 + idx] = *(uint4*)&h.u[0];
      wB[1536 + idx] = *(uint4*)&lo.u[0];
    } else if (idx < 1280) {  // B1 frags, virtual K=32: [Bh|Bh] and [Bl|0]
      int s = idx - 1024;
      int l = s & 63;
      int colw = (s >> 6) * 16 + (l & 15), qw = l >> 4;
      BF8 hh, l0;
#pragma unroll
      for (int i = 0; i < 8; ++i) {
        int kk = qw * 8 + i, k = kk & 15;
        float w = (k < 11) ? W1[k * 64 + colw] : 0.0f;
        unsigned int u = __float_as_uint(w);
        unsigned short whi = (unsigned short)(u >> 16);
        float e = w - __uint_as_float(u & 0xffff0000u);
        unsigned short wlo = (unsigned short)(__float_as_uint(e) >> 16);
        hh.u[i] = whi;
        l0.u[i] = (kk < 16) ? wlo : (unsigned short)0;
      }
      wB[s] = *(uint4*)&hh.u[0];
      wB[256 + s] = *(uint4*)&l0.u[0];
    }
    return;
  }
  __shared__ unsigned int tmp[256];
  __shared__ unsigned int sBase;
  int t = threadIdx.x;
  int tid = b * 256 + t;
  unsigned int myc = cnt[tid];
  tmp[t] = myc;
  __syncthreads();
  for (int off = 1; off < 256; off <<= 1) {  // inclusive block scan
    unsigned int x = (t >= off) ? tmp[t - off] : 0u;
    __syncthreads();
    tmp[t] += x;
    __syncthreads();
  }
  if (t == 255) sBase = atomicAdd(total, tmp[255]);
  __syncthreads();
  cursor[tid] = sBase + tmp[t] - myc;  // base of this voxel's run
  if (myc == 0u) {                     // zero-fill empty voxel rows
    float4 z = float4{0.f, 0.f, 0.f, 0.f};
    float4* o = out4 + (size_t)tid * 16;
#pragma unroll
    for (int i = 0; i < 16; ++i) o[i] = z;
  }
}

// ---------------- scatter: atomic-free (cursor base + cached rank) ---------
__global__ void k_scatter(const unsigned int* __restrict__ vid,
                          const unsigned int* __restrict__ cursor,
                          uint2* __restrict__ pv, int n) {
  int p = blockIdx.x * blockDim.x + threadIdx.x;
  if (p >= n) return;
  unsigned int vr = vid[p];
  unsigned int v = vr & 0x7FFFFu;
  unsigned int pos = cursor[v] + (vr >> 19);
  pv[pos] = uint2{(unsigned int)p, v};
}

// ---------------- fused VFE ----------------
// 7 blocks/CU (LDS ~22.7KB -> 23040). This round (r12): (1) barrier BC->D
// deleted (4 barriers): D derives its run bounds [r0,r1) from the register
// masks m0/m1 (r2-verified clz/ffs derivation) instead of the LDS slot
// tables; tables are still written in BC but first READ after the D-end
// barrier (F/G). (2) E statically unrolled 5x with g<ngr guards so the
// compiler pipelines group g+1's ds_read under group g's MFMA+epilogue.
__global__ __launch_bounds__(256, 7) void k_fused(
    const float4* __restrict__ feat,
    const uint2* __restrict__ pv,
    const uint4* __restrict__ wB,
    const float* __restrict__ scale1, const float* __restrict__ shift1,
    const float* __restrict__ scale2, const float* __restrict__ shift2,
    float* __restrict__ out, int n) {
  __shared__ __align__(16) float Fraw[4][FrW];  // raw features, SoA (A..D)
  __shared__ __align__(16) union {
    unsigned short Ph[NPmax][PhS];     // pf1, bf16 (E..G-prep)
    float Cst[4][16][20];              // per-wave GEMM2 C staging (post-bar G)
  } uP;                                // Ph dead after G-prep -> overlay legal
  __shared__ __align__(16) union {
    struct {
      unsigned short Fsp[NPmax][40];   // split feats [hi k0..15|lo k16..31]
      unsigned int gvid2[FrW];         // vid window (phases A..D)
    } a;
    unsigned short Vh[NPmax][PhS];     // per-slot vmax(pf1), bf16 (F..G)
  } uB;
  __shared__ short slot_of[NPmax];
  __shared__ short slot_start[NPmax + 1];
  __shared__ unsigned int slot_vox[NPmax];

  int t = threadIdx.x;
  int lane = t & 63, wv = t >> 6;
  int m = lane & 15, q = lane >> 4;
  int col = wv * 16 + m;
  long long i0n = (long long)blockIdx.x * P;
  unsigned int* gvid = uB.a.gvid2;

  // GEMM1 fragments + epilogue constants (prepped; coalesced 16B loads)
  BF8 b1hh, b1l0;
  *(uint4*)&b1hh.u[0] = wB[wv * 64 + lane];
  *(uint4*)&b1l0.u[0] = wB[256 + wv * 64 + lane];
  float s1 = scale1[col], sh1 = shift1[col];

  // A: window load (sorted-order gather), W=89 entries
  if (t < W) {
    long long pos = i0n - 1 + t;
    unsigned int v = 0xFFFFFFFFu;
    float4 f = float4{0.f, 0.f, 0.f, 0.f};
    if (pos >= 0 && pos < n) {
      uint2 e = pv[pos];
      v = e.y;
      f = feat[e.x];
    }
    gvid[t] = v;
    Fraw[0][t] = f.x; Fraw[1][t] = f.y;
    Fraw[2][t] = f.z; Fraw[3][t] = f.w;
  }
  __syncthreads();

  // B+C fused: every wave redundantly computes range + boundary masks
  unsigned long long m0, m1;
  int s_off, np;
  {
    bool eq = (blockIdx.x > 0) && (gvid[1 + lane] == gvid[0]);
    unsigned long long mm = __ballot(eq);
    s_off = (~mm == 0ull) ? 64 : (__ffsll((long long)~mm) - 1);
    unsigned int lastv = gvid[P];
    bool eq2 = (1 + P + lane < W) && (lastv != 0xFFFFFFFFu) &&
               (gvid[1 + P + lane] == lastv);
    unsigned long long m2 = __ballot(eq2);
    int e_off = __ffsll((long long)~m2) - 1;  // lane63 false -> well-defined
    long long ecap = (long long)(P + e_off);
    if (ecap > n - i0n) ecap = n - i0n;
    np = (int)ecap - s_off;
    if (np > NPmax) np = NPmax;
    bool b0 = (lane < np) &&
              (lane == 0 || gvid[1 + s_off + lane] != gvid[s_off + lane]);
    m0 = __ballot(b0);
    int j1 = 64 + lane;
    bool b1v = (j1 < np) && (gvid[1 + s_off + j1] != gvid[s_off + j1]);
    m1 = __ballot(b1v);
  }
  if (np <= 0) return;
  int ns = __popcll(m0) + __popcll(m1);
  if (t < np) {
    int j = t;
    int slot = (j < 64) ? (__popcll(m0 << (63 - j)) - 1)
                        : (__popcll(m0) + __popcll(m1 << (63 - (j - 64))) - 1);
    slot_of[j] = (short)slot;
    bool bf = (j == 0) || (gvid[1 + s_off + j] != gvid[s_off + j]);
    if (bf) {
      slot_start[slot] = (short)j;
      slot_vox[slot] = gvid[1 + s_off + j];
    }
  }
  if (t == 0) slot_start[ns] = (short)np;
  // NO barrier: D below derives its bounds from register masks; the slot
  // tables written above are first read after the D-end barrier (F/G).

  // D: per-point features -> split-bf16 A rows (trunc hi, resid lo).
  // Run bounds [r0,r1) from m0/m1 registers (r2-verified derivation).
  if (t < np) {
    int j = t;
    int r0, r1;
    if (j < 64) {
      unsigned long long mlow =
          (j == 63) ? m0 : (m0 & ((1ull << (j + 1)) - 1ull));
      r0 = 63 - __clzll((long long)mlow);  // bit0 of m0 always set
      unsigned long long mh = (j == 63) ? 0ull : (m0 >> (j + 1));
      if (mh) r1 = (j + 1) + (__ffsll((long long)mh) - 1);
      else if (m1) r1 = 64 + (__ffsll((long long)m1) - 1);
      else r1 = np;
    } else {
      int j2 = j - 64;
      unsigned long long mlow1 =
          (j2 == 63) ? m1 : (m1 & ((1ull << (j2 + 1)) - 1ull));
      if (mlow1) r0 = 64 + 63 - __clzll((long long)mlow1);
      else r0 = 63 - __clzll((long long)m0);
      unsigned long long mh = (j2 == 63) ? 0ull : (m1 >> (j2 + 1));
      r1 = mh ? 64 + j2 + 1 + (__ffsll((long long)mh) - 1) : np;
    }
    float sx = 0.f, sy = 0.f, sz = 0.f;
    for (int jr0 = r0; jr0 < r1; ++jr0) {
      int jr = 1 + s_off + jr0;
      sx += Fraw[0][jr]; sy += Fraw[1][jr]; sz += Fraw[2][jr];
    }
    float rc = 1.0f / (float)(r1 - r0);
    int jw = 1 + s_off + t;
    float fx = Fraw[0][jw], fy = Fraw[1][jw];
    float fz = Fraw[2][jw], fr = Fraw[3][jw];
    unsigned int v = gvid[jw];
    unsigned int cx = v % (unsigned int)kCX;
    unsigned int cy = (v / (unsigned int)kCX) % (unsigned int)kCY;
    float f[12];
    f[0] = fx; f[1] = fy; f[2] = fz; f[3] = fr;
    f[4] = fx - sx * rc; f[5] = fy - sy * rc; f[6] = fz - sz * rc;
    f[7] = fx - ((float)cx * kVX + kXOFF);
    f[8] = fy - ((float)cy * kVY + kYOFF);
    f[9] = fz - kZOFF;
    f[10] = sqrtf(fx * fx + fy * fy + fz * fz);
    f[11] = 0.0f;
    unsigned int H[6], L[6];
#pragma unroll
    for (int i2 = 0; i2 < 6; ++i2) {
      unsigned int ua = __float_as_uint(f[2 * i2]);
      unsigned int ub = __float_as_uint(f[2 * i2 + 1]);
      H[i2] = (ua >> 16) | (ub & 0xffff0000u);
      float ea = f[2 * i2] - __uint_as_float(ua & 0xffff0000u);
      float eb = f[2 * i2 + 1] - __uint_as_float(ub & 0xffff0000u);
      L[i2] = (__float_as_uint(ea) >> 16) | (__float_as_uint(eb) & 0xffff0000u);
    }
    *(uint4*)&uB.a.Fsp[t][0] = uint4{H[0], H[1], H[2], H[3]};
    *(uint4*)&uB.a.Fsp[t][8] = uint4{H[4], H[5], 0u, 0u};
    *(uint4*)&uB.a.Fsp[t][16] = uint4{L[0], L[1], L[2], L[3]};
    *(uint4*)&uB.a.Fsp[t][24] = uint4{L[4], L[5], 0u, 0u};
  }
  __syncthreads();  // covers slot tables + Fsp

  // E: GEMM1 on MFMA. A=[Ah|Al] (K=32 virtual); B1hh=[Bh|Bh], B1l0=[Bl|0]
  //    Statically unrolled (5 groups, g<ngr guards) for SW pipelining.
  //    Stores guarded by row < np (pads never read).
  {
    int ngr = (np + 15) >> 4;
#pragma unroll
    for (int g = 0; g < 5; ++g) {
      if (g < ngr) {
        int base = g << 4;
        int jj = base + m;
        if (jj >= np) jj = np - 1;   // clamp reads
        BF8 a;
        *(uint4*)&a.u[0] = *(const uint4*)&uB.a.Fsp[jj][q * 8];
        f32x4 c = {0.f, 0.f, 0.f, 0.f};
        __builtin_amdgcn_s_setprio(1);
        c = __builtin_amdgcn_mfma_f32_16x16x32_bf16(a.v, b1hh.v, c, 0, 0, 0);
        c = __builtin_amdgcn_mfma_f32_16x16x32_bf16(a.v, b1l0.v, c, 0, 0, 0);
        __builtin_amdgcn_s_setprio(0);
        float v0 = fmaxf(c[0] * s1 + sh1, 0.0f);
        float v1 = fmaxf(c[1] * s1 + sh1, 0.0f);
        float v2 = fmaxf(c[2] * s1 + sh1, 0.0f);
        float v3 = fmaxf(c[3] * s1 + sh1, 0.0f);
        unsigned int p01 = cvt_pk_bf16(v0, v1);
        unsigned int p23 = cvt_pk_bf16(v2, v3);
        int row = base + 4 * q;
        if (row < np) uP.Ph[row][col] = (unsigned short)p01;
        if (row + 1 < np) uP.Ph[row + 1][col] = (unsigned short)(p01 >> 16);
        if (row + 2 < np) uP.Ph[row + 2][col] = (unsigned short)p23;
        if (row + 3 < np) uP.Ph[row + 3][col] = (unsigned short)(p23 >> 16);
      }
    }
  }
  __syncthreads();

  // F: per-slot vmax of pf1 -> uB.Vh (overwrites dead Fsp/gvid). Thread
  // (cg,sp) owns 4 cols x slot-stride-16. bf16>=0 so u16 cmp == value cmp.
  {
    int cg = t & 15, sp = t >> 4;
    for (int s = sp; s < ns; s += 16) {
      int a0 = slot_start[s], a1 = slot_start[s + 1];
      ushort4 mx = ushort4{0, 0, 0, 0};
      for (int j = a0; j < a1; ++j) {
        ushort4 x = *(const ushort4*)&uP.Ph[j][cg * 4];
        mx.x = x.x > mx.x ? x.x : mx.x;
        mx.y = x.y > mx.y ? x.y : mx.y;
        mx.z = x.z > mx.z ? x.z : mx.z;
        mx.w = x.w > mx.w ? x.w : mx.w;
      }
      *(ushort4*)&uB.Vh[s][cg * 4] = mx;
    }
  }

  // G-prep (PRE-barrier): Ph-side GEMM2 MFMAs for all groups. Groups are
  // FIXED 16-row blocks: ng = ceil(np/16) <= 5 provably (np <= 76).
  BF8 b2h[4], b2l[4];
#pragma unroll
  for (int kb = 0; kb < 4; ++kb) {
    *(uint4*)&b2h[kb].u[0] = wB[512 + (wv * 4 + kb) * 64 + lane];
    *(uint4*)&b2l[kb].u[0] = wB[1536 + (wv * 4 + kb) * 64 + lane];
  }
  int ng = (np + 15) >> 4;  // <= 5
  f32x4 c2a[5];
#pragma unroll
  for (int g = 0; g < 5; ++g) {
    c2a[g] = f32x4{0.f, 0.f, 0.f, 0.f};
    if (g < ng) {
      int jj = (g << 4) + m;
      if (jj > np - 1) jj = np - 1;
      __builtin_amdgcn_s_setprio(1);
#pragma unroll
      for (int kb = 0; kb < 2; ++kb) {
        const unsigned short* ph = &uP.Ph[jj][kb * 32 + q * 8];
        BF8 a;
        *(ushort4*)&a.u[0] = *(const ushort4*)ph;
        *(ushort4*)&a.u[4] = *(const ushort4*)(ph + 4);
        c2a[g] =
            __builtin_amdgcn_mfma_f32_16x16x32_bf16(a.v, b2h[kb].v, c2a[g], 0, 0, 0);
        c2a[g] =
            __builtin_amdgcn_mfma_f32_16x16x32_bf16(a.v, b2l[kb].v, c2a[g], 0, 0, 0);
      }
      __builtin_amdgcn_s_setprio(0);
    }
  }
  __syncthreads();  // Vh ready; Ph reads complete -> Cst overlay legal

  // G: Vh-side MFMAs + epilogue + per-slot reduce + store. Spanning slots
  // (run crossing a 16-row group boundary) are merged via a register carry:
  // partial max is shfl-broadcast from the s_hi lane and folded in by the
  // next group's s_lo lane; only the final group stores the row.
  float s2 = scale2[col], sh2 = shift2[col];
  int rcg = lane & 3, rsp = lane >> 2;  // reduce: 1 slot/lane, 4 cols/lane
  float cr0 = 0.f, cr1 = 0.f, cr2 = 0.f, cr3 = 0.f;
#pragma unroll
  for (int g = 0; g < 5; ++g) {
    if (g < ng) {
      int base = g << 4;
      int lim = base + 16;
      if (lim > np) lim = np;
      int jj = base + m;
      if (jj > np - 1) jj = np - 1;  // pad rows (ignored in reduce)
      int sl = slot_of[jj];
      f32x4 c2b = {0.f, 0.f, 0.f, 0.f};
      __builtin_amdgcn_s_setprio(1);
#pragma unroll
      for (int kb = 0; kb < 2; ++kb) {
        const unsigned short* ph = &uB.Vh[sl][kb * 32 + q * 8];
        BF8 a;
        *(ushort4*)&a.u[0] = *(const ushort4*)ph;
        *(ushort4*)&a.u[4] = *(const ushort4*)(ph + 4);
        c2b = __builtin_amdgcn_mfma_f32_16x16x32_bf16(a.v, b2h[2 + kb].v, c2b,
                                                      0, 0, 0);
        c2b = __builtin_amdgcn_mfma_f32_16x16x32_bf16(a.v, b2l[2 + kb].v, c2b,
                                                      0, 0, 0);
      }
      __builtin_amdgcn_s_setprio(0);
      // per-wave private transpose (same-wave LDS RAW in-order: no barrier)
#pragma unroll
      for (int r = 0; r < 4; ++r)
        uP.Cst[wv][q * 4 + r][m] =
            fmaxf((c2a[g][r] + c2b[r]) * s2 + sh2, 0.0f);
      int s_lo = slot_of[base], s_hi = slot_of[lim - 1];
      int s = s_lo + rsp;
      bool have = (s <= s_hi);
      f32x4 mx = {0.f, 0.f, 0.f, 0.f};
      if (have) {
        int a0 = slot_start[s];
        if (a0 < base) a0 = base;  // clipped: pre-base part came via carry
        int a1 = slot_start[s + 1];
        if (a1 > lim) a1 = lim;
        for (int j = a0; j < a1; ++j) {
          f32x4 v = *(const f32x4*)&uP.Cst[wv][j - base][rcg * 4];
#pragma unroll
          for (int c = 0; c < 4; ++c) mx[c] = fmaxf(mx[c], v[c]);
        }
        if (rsp == 0 && (int)slot_start[s_lo] < base) {  // merge carry-in
          mx[0] = fmaxf(mx[0], cr0); mx[1] = fmaxf(mx[1], cr1);
          mx[2] = fmaxf(mx[2], cr2); mx[3] = fmaxf(mx[3], cr3);
        }
      }
      bool spans = ((int)slot_start[s_hi + 1] > lim);  // wave-uniform
      int srclane = ((s_hi - s_lo) << 2) | rcg;
      float n0 = __shfl(mx[0], srclane, 64);
      float n1 = __shfl(mx[1], srclane, 64);
      float n2 = __shfl(mx[2], srclane, 64);
      float n3 = __shfl(mx[3], srclane, 64);
      cr0 = spans ? n0 : 0.f; cr1 = spans ? n1 : 0.f;
      cr2 = spans ? n2 : 0.f; cr3 = spans ? n3 : 0.f;
      if (have && !(spans && rsp == (s_hi - s_lo))) {
        *(float4*)&out[(size_t)slot_vox[s] * 64 + wv * 16 + rcg * 4] =
            float4{mx[0], mx[1], mx[2], mx[3]};
      }
    }
  }
}

extern "C" void kernel_launch(void* const* d_in, const int* in_sizes, int n_in,
                              void* d_out, int out_size, void* d_ws, size_t ws_size,
                              hipStream_t stream) {
  const float4* feat = (const float4*)d_in[0];
  const int4* coors = (const int4*)d_in[1];
  const float* W1 = (const float*)d_in[2];
  const float* scale1 = (const float*)d_in[3];
  const float* shift1 = (const float*)d_in[4];
  const float* W2 = (const float*)d_in[5];
  const float* scale2 = (const float*)d_in[6];
  const float* shift2 = (const float*)d_in[7];
  int n = in_sizes[0] / 4;  // 500000 points

  // Workspace (~8.4 MB): cnt[kCL] | total[16] | cursor[kCL] | vid[n] | pv[n]
  //                    | wB (40 KB prepped bf16 weight fragments)
  unsigned int* cnt = (unsigned int*)d_ws;
  unsigned int* total = cnt + kCL;
  unsigned int* cursor = total + 16;
  unsigned int* vid = cursor + kCL;
  uint2* pv = (uint2*)(vid + ((n + 3) & ~3));
  uint4* wB = (uint4*)(pv + n);

  // zero cnt + total in one memset
  hipMemsetAsync(cnt, 0, (size_t)(kCL + 16) * 4, stream);

  k_hist<<<(n + 255) / 256, 256, 0, stream>>>(coors, cnt, vid, n);
  k_alloczero<<<NBLK + NPREP, 256, 0, stream>>>(cnt, total, cursor,
                                                (float4*)d_out, W1, W2, wB);
  k_scatter<<<(n + 255) / 256, 256, 0, stream>>>(vid, cursor, pv, n);
  k_fused<<<(n + P - 1) / P, 256, 0, stream>>>(
      feat, pv, wB, scale1, shift1, scale2, shift2, (float*)d_out, n);
}

// Round 13
// 197.890 us; speedup vs baseline: 1.0092x; 1.0092x over previous
//
#include <hip/hip_runtime.h>

typedef __bf16 bf16x8 __attribute__((ext_vector_type(8)));
typedef float f32x4 __attribute__((ext_vector_type(4)));

namespace {
constexpr int kCX = 352, kCY = 400;
constexpr int kCL = 2 * kCY * kCX;   // 281600 voxels (CZ==1), < 2^19
constexpr float kVX = 0.2f, kVY = 0.2f;
constexpr float kXOFF = 0.1f;    // VX/2 + X0
constexpr float kYOFF = -39.9f;  // VY/2 + Y0
constexpr float kZOFF = -1.0f;   // VZ/2 + Z0 (cz==0 always)
constexpr int P = 64;            // sorted points per fused block
constexpr int W = 89;            // window entries: 1 + P + 24 extension
constexpr int FrW = 90;          // Fraw width (reads bounded by ecap <= 88)
constexpr int NPmax = 76;        // capacity incl. voxel-straddle (max run ~12)
constexpr int NBLK = kCL / 256;  // 1100 alloc blocks (1 thread : 1 voxel)
constexpr int NPREP = 5;         // extra alloczero blocks: weight-frag prep
constexpr int PhS = 68;          // Ph/Vh row stride u16 (136B = 34dw, 2-way free)
}

__device__ __forceinline__ unsigned int cvt_pk_bf16(float lo, float hi) {
  unsigned int r;
  asm("v_cvt_pk_bf16_f32 %0, %1, %2" : "=v"(r) : "v"(lo), "v"(hi));
  return r;  // packed {hi16=bf16(hi), lo16=bf16(lo)}, RNE
}

union BF8 { unsigned short u[8]; bf16x8 v; };

__device__ __forceinline__ int voxel_of(int4 c) {
  return ((c.x + c.y) * kCY + c.z) * kCX + c.w;  // CZ==1
}

// ---------------- hist: counts + {vid | rank<<19} cache ----------------
__global__ void k_hist(const int4* __restrict__ coors,
                       unsigned int* __restrict__ cnt,
                       unsigned int* __restrict__ vid, int n) {
  int p = blockIdx.x * blockDim.x + threadIdx.x;
  if (p >= n) return;
  int v = voxel_of(coors[p]);
  unsigned int r = atomicAdd(&cnt[v], 1u);
  vid[p] = (unsigned int)v | (r << 19);
}

// ------- alloc: block-local scan + ONE relaxed atomicAdd per block --------
// Blocks >= NBLK prepack W1/W2 into per-lane bf16 hi/lo MFMA fragments.
// wB layout (uint4 units): [B1hh 4*64 | B1l0 4*64 | B2h 16*64 | B2l 16*64]
__global__ __launch_bounds__(256) void k_alloczero(
    const unsigned int* __restrict__ cnt,
    unsigned int* __restrict__ total,
    unsigned int* __restrict__ cursor,
    float4* __restrict__ out4,
    const float* __restrict__ W1,
    const float* __restrict__ W2,
    uint4* __restrict__ wB) {
  int b = blockIdx.x;
  if (b >= NBLK) {  // ---- weight prep path ----
    int idx = (b - NBLK) * 256 + threadIdx.x;
    if (idx < 1024) {  // B2 frags: idx = (cb*4+kb)*64 + l
      int kb = (idx >> 6) & 3, l = idx & 63;
      int colw = (idx >> 8) * 16 + (l & 15), qw = l >> 4;
      BF8 h, lo;
#pragma unroll
      for (int i = 0; i < 8; ++i) {
        float w = W2[(kb * 32 + qw * 8 + i) * 64 + colw];
        unsigned int u = __float_as_uint(w);
        h.u[i] = (unsigned short)(u >> 16);           // trunc hi
        float e = w - __uint_as_float(u & 0xffff0000u);
        lo.u[i] = (unsigned short)(__float_as_uint(e) >> 16);  // resid lo
      }
      wB[512 + idx] = *(uint4*)&h.u[0];
      wB[1536 + idx] = *(uint4*)&lo.u[0];
    } else if (idx < 1280) {  // B1 frags, virtual K=32: [Bh|Bh] and [Bl|0]
      int s = idx - 1024;
      int l = s & 63;
      int colw = (s >> 6) * 16 + (l & 15), qw = l >> 4;
      BF8 hh, l0;
#pragma unroll
      for (int i = 0; i < 8; ++i) {
        int kk = qw * 8 + i, k = kk & 15;
        float w = (k < 11) ? W1[k * 64 + colw] : 0.0f;
        unsigned int u = __float_as_uint(w);
        unsigned short whi = (unsigned short)(u >> 16);
        float e = w - __uint_as_float(u & 0xffff0000u);
        unsigned short wlo = (unsigned short)(__float_as_uint(e) >> 16);
        hh.u[i] = whi;
        l0.u[i] = (kk < 16) ? wlo : (unsigned short)0;
      }
      wB[s] = *(uint4*)&hh.u[0];
      wB[256 + s] = *(uint4*)&l0.u[0];
    }
    return;
  }
  __shared__ unsigned int tmp[256];
  __shared__ unsigned int sBase;
  int t = threadIdx.x;
  int tid = b * 256 + t;
  unsigned int myc = cnt[tid];
  tmp[t] = myc;
  __syncthreads();
  for (int off = 1; off < 256; off <<= 1) {  // inclusive block scan
    unsigned int x = (t >= off) ? tmp[t - off] : 0u;
    __syncthreads();
    tmp[t] += x;
    __syncthreads();
  }
  if (t == 255) sBase = atomicAdd(total, tmp[255]);
  __syncthreads();
  cursor[tid] = sBase + tmp[t] - myc;  // base of this voxel's run
  if (myc == 0u) {                     // zero-fill empty voxel rows
    float4 z = float4{0.f, 0.f, 0.f, 0.f};
    float4* o = out4 + (size_t)tid * 16;
#pragma unroll
    for (int i = 0; i < 16; ++i) o[i] = z;
  }
}

// ---------------- scatter: atomic-free (cursor base + cached rank) ---------
__global__ void k_scatter(const unsigned int* __restrict__ vid,
                          const unsigned int* __restrict__ cursor,
                          uint2* __restrict__ pv, int n) {
  int p = blockIdx.x * blockDim.x + threadIdx.x;
  if (p >= n) return;
  unsigned int vr = vid[p];
  unsigned int v = vr & 0x7FFFFu;
  unsigned int pos = cursor[v] + (vr >> 19);
  pv[pos] = uint2{(unsigned int)p, v};
}

// ---------------- fused VFE (r11 verbatim — session best, 64.5 us) --------
// 7 blocks/CU (LDS ~22.7KB -> 23040 granule). FIXED 16-row groups
// (ng = ceil(np/16) <= 5 provably), spanning slots merged across groups via
// a register carry + __shfl (exactly one store per voxel row).
__global__ __launch_bounds__(256, 7) void k_fused(
    const float4* __restrict__ feat,
    const uint2* __restrict__ pv,
    const uint4* __restrict__ wB,
    const float* __restrict__ scale1, const float* __restrict__ shift1,
    const float* __restrict__ scale2, const float* __restrict__ shift2,
    float* __restrict__ out, int n) {
  __shared__ __align__(16) float Fraw[4][FrW];  // raw features, SoA (A..D)
  __shared__ __align__(16) union {
    unsigned short Ph[NPmax][PhS];     // pf1, bf16 (E..G-prep)
    float Cst[4][16][20];              // per-wave GEMM2 C staging (post-bar G)
  } uP;                                // Ph dead after G-prep -> overlay legal
  __shared__ __align__(16) union {
    struct {
      unsigned short Fsp[NPmax][40];   // split feats [hi k0..15|lo k16..31]
      unsigned int gvid2[FrW];         // vid window (phases A..D)
    } a;
    unsigned short Vh[NPmax][PhS];     // per-slot vmax(pf1), bf16 (F..G)
  } uB;
  __shared__ short slot_of[NPmax];
  __shared__ short slot_start[NPmax + 1];
  __shared__ unsigned int slot_vox[NPmax];

  int t = threadIdx.x;
  int lane = t & 63, wv = t >> 6;
  int m = lane & 15, q = lane >> 4;
  int col = wv * 16 + m;
  long long i0n = (long long)blockIdx.x * P;
  unsigned int* gvid = uB.a.gvid2;

  // GEMM1 fragments + epilogue constants (prepped; coalesced 16B loads)
  BF8 b1hh, b1l0;
  *(uint4*)&b1hh.u[0] = wB[wv * 64 + lane];
  *(uint4*)&b1l0.u[0] = wB[256 + wv * 64 + lane];
  float s1 = scale1[col], sh1 = shift1[col];

  // A: window load (sorted-order gather), W=89 entries
  if (t < W) {
    long long pos = i0n - 1 + t;
    unsigned int v = 0xFFFFFFFFu;
    float4 f = float4{0.f, 0.f, 0.f, 0.f};
    if (pos >= 0 && pos < n) {
      uint2 e = pv[pos];
      v = e.y;
      f = feat[e.x];
    }
    gvid[t] = v;
    Fraw[0][t] = f.x; Fraw[1][t] = f.y;
    Fraw[2][t] = f.z; Fraw[3][t] = f.w;
  }
  __syncthreads();

  // B+C fused: every wave redundantly computes range + boundary masks
  unsigned long long m0, m1;
  int s_off, np;
  {
    bool eq = (blockIdx.x > 0) && (gvid[1 + lane] == gvid[0]);
    unsigned long long mm = __ballot(eq);
    s_off = (~mm == 0ull) ? 64 : (__ffsll((long long)~mm) - 1);
    unsigned int lastv = gvid[P];
    bool eq2 = (1 + P + lane < W) && (lastv != 0xFFFFFFFFu) &&
               (gvid[1 + P + lane] == lastv);
    unsigned long long m2 = __ballot(eq2);
    int e_off = __ffsll((long long)~m2) - 1;  // lane63 false -> well-defined
    long long ecap = (long long)(P + e_off);
    if (ecap > n - i0n) ecap = n - i0n;
    np = (int)ecap - s_off;
    if (np > NPmax) np = NPmax;
    bool b0 = (lane < np) &&
              (lane == 0 || gvid[1 + s_off + lane] != gvid[s_off + lane]);
    m0 = __ballot(b0);
    int j1 = 64 + lane;
    bool b1v = (j1 < np) && (gvid[1 + s_off + j1] != gvid[s_off + j1]);
    m1 = __ballot(b1v);
  }
  if (np <= 0) return;
  int ns = __popcll(m0) + __popcll(m1);
  if (t < np) {
    int j = t;
    int slot = (j < 64) ? (__popcll(m0 << (63 - j)) - 1)
                        : (__popcll(m0) + __popcll(m1 << (63 - (j - 64))) - 1);
    slot_of[j] = (short)slot;
    bool bf = (j == 0) || (gvid[1 + s_off + j] != gvid[s_off + j]);
    if (bf) {
      slot_start[slot] = (short)j;
      slot_vox[slot] = gvid[1 + s_off + j];
    }
  }
  if (t == 0) slot_start[ns] = (short)np;
  __syncthreads();

  // D: per-point features -> split-bf16 A rows (trunc hi, resid lo)
  if (t < np) {
    int s = slot_of[t];
    int a0 = slot_start[s], a1 = slot_start[s + 1];
    float sx = 0.f, sy = 0.f, sz = 0.f;
    for (int j = a0; j < a1; ++j) {
      int jr = 1 + s_off + j;
      sx += Fraw[0][jr]; sy += Fraw[1][jr]; sz += Fraw[2][jr];
    }
    float rc = 1.0f / (float)(a1 - a0);
    int jw = 1 + s_off + t;
    float fx = Fraw[0][jw], fy = Fraw[1][jw];
    float fz = Fraw[2][jw], fr = Fraw[3][jw];
    unsigned int v = gvid[jw];
    unsigned int cx = v % (unsigned int)kCX;
    unsigned int cy = (v / (unsigned int)kCX) % (unsigned int)kCY;
    float f[12];
    f[0] = fx; f[1] = fy; f[2] = fz; f[3] = fr;
    f[4] = fx - sx * rc; f[5] = fy - sy * rc; f[6] = fz - sz * rc;
    f[7] = fx - ((float)cx * kVX + kXOFF);
    f[8] = fy - ((float)cy * kVY + kYOFF);
    f[9] = fz - kZOFF;
    f[10] = sqrtf(fx * fx + fy * fy + fz * fz);
    f[11] = 0.0f;
    unsigned int H[6], L[6];
#pragma unroll
    for (int i2 = 0; i2 < 6; ++i2) {
      unsigned int ua = __float_as_uint(f[2 * i2]);
      unsigned int ub = __float_as_uint(f[2 * i2 + 1]);
      H[i2] = (ua >> 16) | (ub & 0xffff0000u);
      float ea = f[2 * i2] - __uint_as_float(ua & 0xffff0000u);
      float eb = f[2 * i2 + 1] - __uint_as_float(ub & 0xffff0000u);
      L[i2] = (__float_as_uint(ea) >> 16) | (__float_as_uint(eb) & 0xffff0000u);
    }
    *(uint4*)&uB.a.Fsp[t][0] = uint4{H[0], H[1], H[2], H[3]};
    *(uint4*)&uB.a.Fsp[t][8] = uint4{H[4], H[5], 0u, 0u};
    *(uint4*)&uB.a.Fsp[t][16] = uint4{L[0], L[1], L[2], L[3]};
    *(uint4*)&uB.a.Fsp[t][24] = uint4{L[4], L[5], 0u, 0u};
  }
  __syncthreads();

  // E: GEMM1 on MFMA. A=[Ah|Al] (K=32 virtual); B1hh=[Bh|Bh], B1l0=[Bl|0]
  //    Stores guarded by row < np (pads never read).
  {
    int ngr = (np + 15) >> 4;
    for (int g = 0; g < ngr; ++g) {
      int base = g << 4;
      int jj = base + m;
      if (jj >= np) jj = np - 1;   // clamp reads
      BF8 a;
      *(uint4*)&a.u[0] = *(const uint4*)&uB.a.Fsp[jj][q * 8];
      f32x4 c = {0.f, 0.f, 0.f, 0.f};
      __builtin_amdgcn_s_setprio(1);
      c = __builtin_amdgcn_mfma_f32_16x16x32_bf16(a.v, b1hh.v, c, 0, 0, 0);
      c = __builtin_amdgcn_mfma_f32_16x16x32_bf16(a.v, b1l0.v, c, 0, 0, 0);
      __builtin_amdgcn_s_setprio(0);
      float v0 = fmaxf(c[0] * s1 + sh1, 0.0f);
      float v1 = fmaxf(c[1] * s1 + sh1, 0.0f);
      float v2 = fmaxf(c[2] * s1 + sh1, 0.0f);
      float v3 = fmaxf(c[3] * s1 + sh1, 0.0f);
      unsigned int p01 = cvt_pk_bf16(v0, v1);
      unsigned int p23 = cvt_pk_bf16(v2, v3);
      int row = base + 4 * q;
      if (row < np) uP.Ph[row][col] = (unsigned short)p01;
      if (row + 1 < np) uP.Ph[row + 1][col] = (unsigned short)(p01 >> 16);
      if (row + 2 < np) uP.Ph[row + 2][col] = (unsigned short)p23;
      if (row + 3 < np) uP.Ph[row + 3][col] = (unsigned short)(p23 >> 16);
    }
  }
  __syncthreads();

  // F: per-slot vmax of pf1 -> uB.Vh (overwrites dead Fsp/gvid). Thread
  // (cg,sp) owns 4 cols x slot-stride-16. bf16>=0 so u16 cmp == value cmp.
  {
    int cg = t & 15, sp = t >> 4;
    for (int s = sp; s < ns; s += 16) {
      int a0 = slot_start[s], a1 = slot_start[s + 1];
      ushort4 mx = ushort4{0, 0, 0, 0};
      for (int j = a0; j < a1; ++j) {
        ushort4 x = *(const ushort4*)&uP.Ph[j][cg * 4];
        mx.x = x.x > mx.x ? x.x : mx.x;
        mx.y = x.y > mx.y ? x.y : mx.y;
        mx.z = x.z > mx.z ? x.z : mx.z;
        mx.w = x.w > mx.w ? x.w : mx.w;
      }
      *(ushort4*)&uB.Vh[s][cg * 4] = mx;
    }
  }

  // G-prep (PRE-barrier): Ph-side GEMM2 MFMAs for all groups. Groups are
  // FIXED 16-row blocks: ng = ceil(np/16) <= 5 provably (np <= 76).
  BF8 b2h[4], b2l[4];
#pragma unroll
  for (int kb = 0; kb < 4; ++kb) {
    *(uint4*)&b2h[kb].u[0] = wB[512 + (wv * 4 + kb) * 64 + lane];
    *(uint4*)&b2l[kb].u[0] = wB[1536 + (wv * 4 + kb) * 64 + lane];
  }
  int ng = (np + 15) >> 4;  // <= 5
  f32x4 c2a[5];
#pragma unroll
  for (int g = 0; g < 5; ++g) {
    c2a[g] = f32x4{0.f, 0.f, 0.f, 0.f};
    if (g < ng) {
      int jj = (g << 4) + m;
      if (jj > np - 1) jj = np - 1;
      __builtin_amdgcn_s_setprio(1);
#pragma unroll
      for (int kb = 0; kb < 2; ++kb) {
        const unsigned short* ph = &uP.Ph[jj][kb * 32 + q * 8];
        BF8 a;
        *(ushort4*)&a.u[0] = *(const ushort4*)ph;
        *(ushort4*)&a.u[4] = *(const ushort4*)(ph + 4);
        c2a[g] =
            __builtin_amdgcn_mfma_f32_16x16x32_bf16(a.v, b2h[kb].v, c2a[g], 0, 0, 0);
        c2a[g] =
            __builtin_amdgcn_mfma_f32_16x16x32_bf16(a.v, b2l[kb].v, c2a[g], 0, 0, 0);
      }
      __builtin_amdgcn_s_setprio(0);
    }
  }
  __syncthreads();  // Vh ready; Ph reads complete -> Cst overlay legal

  // G: Vh-side MFMAs + epilogue + per-slot reduce + store. Spanning slots
  // (run crossing a 16-row group boundary) are merged via a register carry:
  // partial max is shfl-broadcast from the s_hi lane and folded in by the
  // next group's s_lo lane; only the final group stores the row.
  float s2 = scale2[col], sh2 = shift2[col];
  int rcg = lane & 3, rsp = lane >> 2;  // reduce: 1 slot/lane, 4 cols/lane
  float cr0 = 0.f, cr1 = 0.f, cr2 = 0.f, cr3 = 0.f;
#pragma unroll
  for (int g = 0; g < 5; ++g) {
    if (g < ng) {
      int base = g << 4;
      int lim = base + 16;
      if (lim > np) lim = np;
      int jj = base + m;
      if (jj > np - 1) jj = np - 1;  // pad rows (ignored in reduce)
      int sl = slot_of[jj];
      f32x4 c2b = {0.f, 0.f, 0.f, 0.f};
      __builtin_amdgcn_s_setprio(1);
#pragma unroll
      for (int kb = 0; kb < 2; ++kb) {
        const unsigned short* ph = &uB.Vh[sl][kb * 32 + q * 8];
        BF8 a;
        *(ushort4*)&a.u[0] = *(const ushort4*)ph;
        *(ushort4*)&a.u[4] = *(const ushort4*)(ph + 4);
        c2b = __builtin_amdgcn_mfma_f32_16x16x32_bf16(a.v, b2h[2 + kb].v, c2b,
                                                      0, 0, 0);
        c2b = __builtin_amdgcn_mfma_f32_16x16x32_bf16(a.v, b2l[2 + kb].v, c2b,
                                                      0, 0, 0);
      }
      __builtin_amdgcn_s_setprio(0);
      // per-wave private transpose (same-wave LDS RAW in-order: no barrier)
#pragma unroll
      for (int r = 0; r < 4; ++r)
        uP.Cst[wv][q * 4 + r][m] =
            fmaxf((c2a[g][r] + c2b[r]) * s2 + sh2, 0.0f);
      int s_lo = slot_of[base], s_hi = slot_of[lim - 1];
      int s = s_lo + rsp;
      bool have = (s <= s_hi);
      f32x4 mx = {0.f, 0.f, 0.f, 0.f};
      if (have) {
        int a0 = slot_start[s];
        if (a0 < base) a0 = base;  // clipped: pre-base part came via carry
        int a1 = slot_start[s + 1];
        if (a1 > lim) a1 = lim;
        for (int j = a0; j < a1; ++j) {
          f32x4 v = *(const f32x4*)&uP.Cst[wv][j - base][rcg * 4];
#pragma unroll
          for (int c = 0; c < 4; ++c) mx[c] = fmaxf(mx[c], v[c]);
        }
        if (rsp == 0 && (int)slot_start[s_lo] < base) {  // merge carry-in
          mx[0] = fmaxf(mx[0], cr0); mx[1] = fmaxf(mx[1], cr1);
          mx[2] = fmaxf(mx[2], cr2); mx[3] = fmaxf(mx[3], cr3);
        }
      }
      bool spans = ((int)slot_start[s_hi + 1] > lim);  // wave-uniform
      int srclane = ((s_hi - s_lo) << 2) | rcg;
      float n0 = __shfl(mx[0], srclane, 64);
      float n1 = __shfl(mx[1], srclane, 64);
      float n2 = __shfl(mx[2], srclane, 64);
      float n3 = __shfl(mx[3], srclane, 64);
      cr0 = spans ? n0 : 0.f; cr1 = spans ? n1 : 0.f;
      cr2 = spans ? n2 : 0.f; cr3 = spans ? n3 : 0.f;
      if (have && !(spans && rsp == (s_hi - s_lo))) {
        *(float4*)&out[(size_t)slot_vox[s] * 64 + wv * 16 + rcg * 4] =
            float4{mx[0], mx[1], mx[2], mx[3]};
      }
    }
  }
}

extern "C" void kernel_launch(void* const* d_in, const int* in_sizes, int n_in,
                              void* d_out, int out_size, void* d_ws, size_t ws_size,
                              hipStream_t stream) {
  const float4* feat = (const float4*)d_in[0];
  const int4* coors = (const int4*)d_in[1];
  const float* W1 = (const float*)d_in[2];
  const float* scale1 = (const float*)d_in[3];
  const float* shift1 = (const float*)d_in[4];
  const float* W2 = (const float*)d_in[5];
  const float* scale2 = (const float*)d_in[6];
  const float* shift2 = (const float*)d_in[7];
  int n = in_sizes[0] / 4;  // 500000 points

  // Workspace (~8.4 MB): cnt[kCL] | total[16] | cursor[kCL] | vid[n] | pv[n]
  //                    | wB (40 KB prepped bf16 weight fragments)
  unsigned int* cnt = (unsigned int*)d_ws;
  unsigned int* total = cnt + kCL;
  unsigned int* cursor = total + 16;
  unsigned int* vid = cursor + kCL;
  uint2* pv = (uint2*)(vid + ((n + 3) & ~3));
  uint4* wB = (uint4*)(pv + n);

  // zero cnt + total in one memset
  hipMemsetAsync(cnt, 0, (size_t)(kCL + 16) * 4, stream);

  k_hist<<<(n + 255) / 256, 256, 0, stream>>>(coors, cnt, vid, n);
  k_alloczero<<<NBLK + NPREP, 256, 0, stream>>>(cnt, total, cursor,
                                                (float4*)d_out, W1, W2, wB);
  k_scatter<<<(n + 255) / 256, 256, 0, stream>>>(vid, cursor, pv, n);
  k_fused<<<(n + P - 1) / P, 256, 0, stream>>>(
      feat, pv, wB, scale1, shift1, scale2, shift2, (float*)d_out, n);
}